// Round 10
// baseline (348.749 us; speedup 1.0000x reference)
//
#include <hip/hip_runtime.h>
#include <cfloat>
#include <math.h>

// Problem constants
#define N_TEXT  226
#define N_IMG   5400
#define N_TOKEN 5626
#define NB_QUANT_BLOCKS 6966   // 27^2 + 36^2 + 45^2 + 54^2
#define NCOPY_A 256
#define NCOPY_B 256
#define HEAD_STRIDE 31651876u  // N_TOKEN*N_TOKEN

// f32(1/15): XLA rewrites divide-by-constant into multiply-by-reciprocal.
#define RCP15 0x1.111112p-4f

typedef float f32x4 __attribute__((ext_vector_type(4)));
typedef float f32x2 __attribute__((ext_vector_type(2)));

// ---------------------------------------------------------------------------
// Locked bit-exact arithmetic (verified r9, absmax=0):
//   scale = fl32(delta * fl32(1/15)); safe = scale==0 ? 1 : scale;
//   recip = fl32(1/safe);  q = clip(roundeven(fl32(x*recip)),0,15);
//   out = fl32(q*scale).
// ---------------------------------------------------------------------------
__device__ __forceinline__ float fq1(float x, float recip, float scale) {
    float q = rintf(__fmul_rn(x, recip));
    q = fminf(fmaxf(q, 0.0f), 15.0f);
    return __fmul_rn(q, scale);
}

// ---------------------------------------------------------------------------
// Quantize one bw x bw tile. Wave-per-row float4 with runtime alignment peel:
// row base elem-offset is always even; off = (-rowbase)&3 in {0,2}. Row =
// [front f2 if off] + nf4 x f4 + [tail f2 if t2]. For BW<=128 each wave
// processes two rows (lane>>5 selects the row) to keep all lanes loading.
// ---------------------------------------------------------------------------
template <int NB>
__device__ __forceinline__ void quant_block(const float* __restrict__ in,
                                            float* __restrict__ out,
                                            int local, int head) {
    constexpr int  BW    = N_IMG / NB;   // 200 / 150 / 120 / 100
    constexpr bool TWO   = (BW <= 128);
    constexpr int  RSTEP = TWO ? 8 : 4;

    const int bi = local / NB;
    const int bj = local - bi * NB;
    const unsigned base = (unsigned)head * HEAD_STRIDE
                        + (unsigned)(N_TEXT + bi * BW) * N_TOKEN
                        + (unsigned)(N_TEXT + bj * BW);
    const float* ip = in + base;
    float*       op = out + base;

    const int tid    = threadIdx.x;
    const int wid    = tid >> 6;
    const int lane   = tid & 63;
    const int subrow = TWO ? (lane >> 5) : 0;
    const int sl     = TWO ? (lane & 31) : lane;
    const int r0     = TWO ? ((wid << 1) + subrow) : wid;

    // ---- pass 1: block max (exact; order-independent) ----
    float m = -FLT_MAX;
    #pragma unroll 2
    for (int r = r0; r < BW; r += RSTEP) {
        const unsigned rowbase = base + (unsigned)r * N_TOKEN;
        const float* rp = ip + (size_t)r * N_TOKEN;
        const int off = (int)((0u - rowbase) & 3u);   // 0 or 2
        const int nf4 = (BW - off) >> 2;
        const int t2  = BW - off - (nf4 << 2);        // 0 or 2
        if (sl < nf4) {
            f32x4 v = *(const f32x4*)(rp + off + (sl << 2));
            m = fmaxf(m, fmaxf(fmaxf(v.x, v.y), fmaxf(v.z, v.w)));
        } else if (sl == nf4 && (off | t2)) {
            const int p = off ? 0 : (nf4 << 2);
            f32x2 v = *(const f32x2*)(rp + p);
            m = fmaxf(m, fmaxf(v.x, v.y));
        } else if (sl == nf4 + 1 && off && t2) {
            const int p = off + (nf4 << 2);
            f32x2 v = *(const f32x2*)(rp + p);
            m = fmaxf(m, fmaxf(v.x, v.y));
        }
    }
    // wave-64 butterfly reduce, then cross-wave via LDS
    #pragma unroll
    for (int o = 32; o > 0; o >>= 1)
        m = fmaxf(m, __shfl_xor(m, o));
    __shared__ float sm[4];
    if (lane == 0) sm[wid] = m;
    __syncthreads();
    const float delta = fmaxf(fmaxf(sm[0], sm[1]), fmaxf(sm[2], sm[3]));

    const float scale = __fmul_rn(delta, RCP15);
    const float safe  = (scale == 0.0f) ? 1.0f : scale;
    const float recip = __fdiv_rn(1.0f, safe);

    // ---- pass 2: fake-quant + nontemporal store (re-read mostly L2-hit) ----
    #pragma unroll 2
    for (int r = r0; r < BW; r += RSTEP) {
        const unsigned rowbase = base + (unsigned)r * N_TOKEN;
        const float* rp = ip + (size_t)r * N_TOKEN;
        float*       wp = op + (size_t)r * N_TOKEN;
        const int off = (int)((0u - rowbase) & 3u);
        const int nf4 = (BW - off) >> 2;
        const int t2  = BW - off - (nf4 << 2);
        if (sl < nf4) {
            f32x4 v = *(const f32x4*)(rp + off + (sl << 2));
            v.x = fq1(v.x, recip, scale);
            v.y = fq1(v.y, recip, scale);
            v.z = fq1(v.z, recip, scale);
            v.w = fq1(v.w, recip, scale);
            __builtin_nontemporal_store(v, (f32x4*)(wp + off + (sl << 2)));
        } else if (sl == nf4 && (off | t2)) {
            const int p = off ? 0 : (nf4 << 2);
            f32x2 v = *(const f32x2*)(rp + p);
            v.x = fq1(v.x, recip, scale);
            v.y = fq1(v.y, recip, scale);
            __builtin_nontemporal_store(v, (f32x2*)(wp + p));
        } else if (sl == nf4 + 1 && off && t2) {
            const int p = off + (nf4 << 2);
            f32x2 v = *(const f32x2*)(rp + p);
            v.x = fq1(v.x, recip, scale);
            v.y = fq1(v.y, recip, scale);
            __builtin_nontemporal_store(v, (f32x2*)(wp + p));
        }
    }
}

// ---------------------------------------------------------------------------
// Region A: rows [0,226) x all cols per head -> contiguous, pure float4.
// ---------------------------------------------------------------------------
__device__ __forceinline__ void copy_text_a(const float* __restrict__ in,
                                            float* __restrict__ out, int cb) {
    const int tid0 = cb * 256 + threadIdx.x;
    for (int j = tid0; j < 4 * 317869; j += NCOPY_A * 256) {
        int head = j / 317869;
        int rem  = j - head * 317869;
        size_t addr = (size_t)head * HEAD_STRIDE + (size_t)rem * 4;
        f32x4 v = *(const f32x4*)(in + addr);
        __builtin_nontemporal_store(v, (f32x4*)(out + addr));
    }
}

// ---------------------------------------------------------------------------
// Region B: rows [226,5626) x cols [0,226), wave-per-row float4 with peel:
// 226 = off + 56*4 + (2-off); exactly one leftover f2 (front or tail).
// ---------------------------------------------------------------------------
__device__ __forceinline__ void copy_text_b(const float* __restrict__ in,
                                            float* __restrict__ out, int cb) {
    const int wid  = threadIdx.x >> 6;
    const int lane = threadIdx.x & 63;
    for (int w = cb * 4 + wid; w < 4 * 5400; w += NCOPY_B * 4) {
        const int head = w / 5400;
        const int r    = w - head * 5400;
        const unsigned rowbase = (unsigned)head * HEAD_STRIDE
                               + (unsigned)(N_TEXT + r) * N_TOKEN;
        const float* rp = in + rowbase;
        float*       wp = out + rowbase;
        const int off = (int)((0u - rowbase) & 3u);   // 0 or 2
        if (lane < 56) {
            f32x4 v = *(const f32x4*)(rp + off + (lane << 2));
            __builtin_nontemporal_store(v, (f32x4*)(wp + off + (lane << 2)));
        } else if (lane == 56) {
            const int p = off ? 0 : 224;
            f32x2 v = *(const f32x2*)(rp + p);
            __builtin_nontemporal_store(v, (f32x2*)(wp + p));
        }
    }
}

// ---------------------------------------------------------------------------
__global__ __launch_bounds__(256)
void qam_kernel(const float* __restrict__ in, float* __restrict__ out) {
    const int b = blockIdx.x;
    if (b < 729) {
        quant_block<27>(in, out, b, 0);
    } else if (b < 2025) {
        quant_block<36>(in, out, b - 729, 1);
    } else if (b < 4050) {
        quant_block<45>(in, out, b - 2025, 2);
    } else if (b < NB_QUANT_BLOCKS) {
        quant_block<54>(in, out, b - 4050, 3);
    } else if (b < NB_QUANT_BLOCKS + NCOPY_A) {
        copy_text_a(in, out, b - NB_QUANT_BLOCKS);
    } else {
        copy_text_b(in, out, b - NB_QUANT_BLOCKS - NCOPY_A);
    }
}

extern "C" void kernel_launch(void* const* d_in, const int* in_sizes, int n_in,
                              void* d_out, int out_size, void* d_ws, size_t ws_size,
                              hipStream_t stream) {
    const float* x = (const float*)d_in[0];
    float* out     = (float*)d_out;
    const int grid = NB_QUANT_BLOCKS + NCOPY_A + NCOPY_B;
    qam_kernel<<<grid, 256, 0, stream>>>(x, out);
}

// Round 11
// 263.291 us; speedup vs baseline: 1.3246x; 1.3246x over previous
//
#include <hip/hip_runtime.h>
#include <cfloat>
#include <math.h>

// Problem constants
#define N_TEXT  226
#define N_IMG   5400
#define N_TOKEN 5626
#define HEAD_STRIDE 31651876u   // N_TOKEN*N_TOKEN
#define HEAD_F4     7912969u    // HEAD_STRIDE/4
#define TOTAL_F4    31651876u   // 4 heads * HEAD_F4

// f32(1/15): XLA rewrites divide-by-constant into multiply-by-reciprocal.
#define RCP15 0x1.111112p-4f

typedef float f32x4 __attribute__((ext_vector_type(4)));
typedef float f32x2 __attribute__((ext_vector_type(2)));

// Locked bit-exact arithmetic (verified r9, absmax=0):
//   scale = fl32(delta*fl32(1/15)); safe = scale==0?1:scale;
//   recip = fl32(1/safe); q = clip(roundeven(fl32(x*recip)),0,15);
//   out = fl32(q*scale).
__device__ __forceinline__ float fq1(float x, float recip, float scale) {
    float q = rintf(__fmul_rn(x, recip));
    q = fminf(fmaxf(q, 0.0f), 15.0f);
    return __fmul_rn(q, scale);
}

// ---------------------------------------------------------------------------
// K1: one block per tile; block max (r9's validated pass-1); thread 0 writes
// {scale, recip} to the ws LUT. Read-only scattered-pattern probe.
// ---------------------------------------------------------------------------
template <int NB, int BASE>
__device__ __forceinline__ void tile_max(const float* __restrict__ in,
                                         float2* __restrict__ scales,
                                         int local, int head) {
    constexpr int BW  = N_IMG / NB;   // 200 / 150 / 120 / 100
    constexpr int NV  = BW / 2;
    constexpr int TOT = BW * NV;
    const int bi = local / NB;
    const int bj = local - bi * NB;
    const size_t base = (size_t)head * HEAD_STRIDE
                      + (size_t)(N_TEXT + bi * BW) * N_TOKEN
                      + (size_t)(N_TEXT + bj * BW);
    const float* ip = in + base;
    const int tid = threadIdx.x;

    float m = -FLT_MAX;
    for (int i = tid; i < TOT; i += 256) {
        int r = i / NV;
        int c = i - r * NV;
        f32x2 v = *(const f32x2*)(ip + (size_t)r * N_TOKEN + 2 * c);
        m = fmaxf(m, fmaxf(v.x, v.y));
    }
    #pragma unroll
    for (int o = 32; o > 0; o >>= 1)
        m = fmaxf(m, __shfl_xor(m, o));
    __shared__ float sm[4];
    if ((tid & 63) == 0) sm[tid >> 6] = m;
    __syncthreads();
    if (tid == 0) {
        const float delta = fmaxf(fmaxf(sm[0], sm[1]), fmaxf(sm[2], sm[3]));
        const float scale = __fmul_rn(delta, RCP15);
        const float safe  = (scale == 0.0f) ? 1.0f : scale;
        const float recip = __fdiv_rn(1.0f, safe);
        scales[BASE + local] = (float2){scale, recip};
    }
}

__global__ __launch_bounds__(256)
void k1_max(const float* __restrict__ in, float2* __restrict__ scales) {
    const int b = blockIdx.x;
    if (b < 729)        tile_max<27, 0>   (in, scales, b,        0);
    else if (b < 2025)  tile_max<36, 729> (in, scales, b - 729,  1);
    else if (b < 4050)  tile_max<45, 2025>(in, scales, b - 2025, 2);
    else                tile_max<54, 4050>(in, scales, b - 4050, 3);
}

// ---------------------------------------------------------------------------
// K2: linear float4 sweep of the whole tensor (reversed order for L3 reuse of
// K1's tail). Text rows/cols copied; image quantized via ws LUT.
// c is always even; straddle cases: c==224 (text|image), c==5624 (row wrap).
// ---------------------------------------------------------------------------
template <int BW, int NB, int BASE>
__device__ __forceinline__ void quant_f4(const float* __restrict__ hin,
                                         float* __restrict__ hout,
                                         const float2* __restrict__ scales,
                                         unsigned e, unsigned r, unsigned c) {
    f32x4 v = *(const f32x4*)(hin + e);
    if (r < N_TEXT) { *(f32x4*)(hout + e) = v; return; }          // text rows
    const unsigned bi = (r - N_TEXT) / BW;
    if (c == 5624u) {                                              // row wrap
        // (r,5624),(r,5625): image, last tile col; (r+1,0),(r+1,1): text copy
        const float2 sr = scales[BASE + bi * NB + (NB - 1)];
        v.x = fq1(v.x, sr.y, sr.x);
        v.y = fq1(v.y, sr.y, sr.x);
        *(f32x4*)(hout + e) = v; return;
    }
    if (c + 3u < N_TEXT) { *(f32x4*)(hout + e) = v; return; }      // c<=222
    if (c == 224u) {                                               // text|image
        const float2 sr = scales[BASE + bi * NB];                  // ic=0,1 -> bj=0
        v.z = fq1(v.z, sr.y, sr.x);
        v.w = fq1(v.w, sr.y, sr.x);
        *(f32x4*)(hout + e) = v; return;
    }
    const unsigned ic  = c - N_TEXT;
    const unsigned bj0 = ic / BW;
    const unsigned bj3 = (ic + 3u) / BW;
    const float2 s0 = scales[BASE + bi * NB + bj0];
    if (bj0 == bj3) {
        v.x = fq1(v.x, s0.y, s0.x);
        v.y = fq1(v.y, s0.y, s0.x);
        v.z = fq1(v.z, s0.y, s0.x);
        v.w = fq1(v.w, s0.y, s0.x);
    } else {                                                       // tile edge
        const float2 s1 = scales[BASE + bi * NB + bj3];
        const unsigned mm = bj3 * BW - ic;     // elems k<mm belong to bj0
        const float2 sy = (1u < mm) ? s0 : s1;
        const float2 sz = (2u < mm) ? s0 : s1;
        v.x = fq1(v.x, s0.y, s0.x);
        v.y = fq1(v.y, sy.y, sy.x);
        v.z = fq1(v.z, sz.y, sz.x);
        v.w = fq1(v.w, s1.y, s1.x);
    }
    *(f32x4*)(hout + e) = v;
}

__global__ __launch_bounds__(256)
void k2_quant(const float* __restrict__ in, float* __restrict__ out,
              const float2* __restrict__ scales) {
    const unsigned i = blockIdx.x * 256u + threadIdx.x;
    if (i >= TOTAL_F4) return;
    const unsigned fi   = TOTAL_F4 - 1u - i;   // reversed: L3 reuse of K1 tail
    const unsigned head = fi / HEAD_F4;
    const unsigned e    = (fi - head * HEAD_F4) * 4u;
    const unsigned r    = e / 5626u;
    const unsigned c    = e - r * 5626u;
    const float* hin  = in  + (size_t)head * HEAD_STRIDE;
    float*       hout = out + (size_t)head * HEAD_STRIDE;
    switch (head) {
        case 0:  quant_f4<200, 27, 0>   (hin, hout, scales, e, r, c); break;
        case 1:  quant_f4<150, 36, 729> (hin, hout, scales, e, r, c); break;
        case 2:  quant_f4<120, 45, 2025>(hin, hout, scales, e, r, c); break;
        default: quant_f4<100, 54, 4050>(hin, hout, scales, e, r, c); break;
    }
}

extern "C" void kernel_launch(void* const* d_in, const int* in_sizes, int n_in,
                              void* d_out, int out_size, void* d_ws, size_t ws_size,
                              hipStream_t stream) {
    const float* x = (const float*)d_in[0];
    float* out     = (float*)d_out;
    float2* scales = (float2*)d_ws;            // 6966 * 8B = 56 KB
    k1_max<<<6966, 256, 0, stream>>>(x, scales);
    const unsigned g2 = (TOTAL_F4 + 255u) / 256u;   // 123641
    k2_quant<<<g2, 256, 0, stream>>>(x, out, scales);
}